// Round 6
// baseline (375.324 us; speedup 1.0000x reference)
//
#include <hip/hip_runtime.h>
#include <hip/hip_bf16.h>
#include <cstddef>

#define NN 50000
#define EE 1600000
#define GG 512
#define NB 196        // ceil(NN/256) buckets of 256 nodes
#define BSTRIDE 16384 // fixed pairs-region capacity per bucket (max span ~8600)
#define BCAP 10240    // LDS staging per bucket
#define XBLKS 6250    // NN*32/256 x-convert blocks
#define SCBLKS 782    // ceil(EE/2048) bscatter blocks
#define PSEG 8        // edge segments per graph in pool3_seg

typedef unsigned int u32;
typedef unsigned short u16;
typedef __attribute__((ext_vector_type(8))) short frag_ab;   // 8 bf16 = 4 VGPRs
typedef __attribute__((ext_vector_type(4))) float frag_cd;   // 4 fp32 acc

__device__ __forceinline__ void gl_lds16(const void* g, void* l) {
    __builtin_amdgcn_global_load_lds(
        (const __attribute__((address_space(1))) u32*)g,
        (__attribute__((address_space(3))) u32*)l, 16, 0, 0);
}
__device__ __forceinline__ float b2f_lo(u32 v) { return __uint_as_float(v << 16); }
__device__ __forceinline__ float b2f_hi(u32 v) { return __uint_as_float(v & 0xffff0000u); }
__device__ __forceinline__ float b2f(u32 v, int odd) { return odd ? b2f_hi(v) : b2f_lo(v); }
__device__ __forceinline__ u16 f2b(float x) {
    __hip_bfloat16 h = __float2bfloat16(x);
    return *(u16*)&h;
}
__device__ __forceinline__ u32 pack2(float lo, float hi) {
    return ((u32)f2b(hi) << 16) | f2b(lo);
}
__device__ __forceinline__ void acc2(float2& a, u32 v) {
    a.x += b2f_lo(v);
    a.y += b2f_hi(v);
}

__device__ inline int lower_bound_i(const int* a, int n, int v) {
    int lo = 0, hi = n;
    while (lo < hi) {
        int m = (lo + hi) >> 1;
        if (a[m] < v) lo = m + 1; else hi = m;
    }
    return lo;
}

// gemm23 rebuilt barrier-light: MFMA frag loads are naturally line-coalesced
// from global (16 rows x 64B per frag-load instr), B matrices are L2-resident
// -> direct-load both operands, no per-kk staging/barriers (64 barriers -> 3).
// C repacked through swizzled LDS for coalesced dwordx4 stores (write
// amplification 60.5 -> ~26 MB).

// ---------------- fused: edge bucket-scatter + x->bf16 + weight prep + gn ----------

__global__ __launch_bounds__(256) void bscatter_prep_kernel(
    const int* __restrict__ ei, int* __restrict__ bcnt, u32* __restrict__ pairs,
    const float* __restrict__ x, u16* __restrict__ ax,
    const float* __restrict__ Wr1, const float* __restrict__ Wo1,
    const float* __restrict__ Wr2, const float* __restrict__ Wo2,
    const float* __restrict__ Wr3, const float* __restrict__ Wo3,
    const float* __restrict__ br3,
    u16* __restrict__ BT1, u16* __restrict__ BT2, u16* __restrict__ BT3,
    float* __restrict__ bias3, const int* __restrict__ batch,
    int* __restrict__ gn) {
    __shared__ int lcnt[NB];
    __shared__ int lbase[NB];
    __shared__ unsigned short lpos[2048];
    int bid = blockIdx.x, t = threadIdx.x;
    if (bid < SCBLKS) {
        int e0 = bid * 2048;
        u32 pk[8];   // packed (src<<8)|(dst&255) stashed across phases
        int bk[8];
        for (int i = t; i < NB; i += 256) lcnt[i] = 0;
        __syncthreads();
#pragma unroll
        for (int i = 0; i < 8; ++i) {
            int e = e0 + i * 256 + t;
            if (e < EE) {
                int dst = ei[EE + e], src = ei[e];
                int b = dst >> 8;
                bk[i] = b;
                pk[i] = ((u32)src << 8) | (u32)(dst & 255);
                lpos[i * 256 + t] = (unsigned short)atomicAdd(&lcnt[b], 1);
            } else bk[i] = -1;
        }
        __syncthreads();
        for (int i = t; i < NB; i += 256) lbase[i] = atomicAdd(&bcnt[i], lcnt[i]);
        __syncthreads();
#pragma unroll
        for (int i = 0; i < 8; ++i) {
            if (bk[i] >= 0) {
                int pos = lbase[bk[i]] + (int)lpos[i * 256 + t];
                pairs[(size_t)bk[i] * BSTRIDE + pos] = pk[i];
            }
        }
    } else if (bid < SCBLKS + XBLKS) {
        int idx = (bid - SCBLKS) * 256 + t;
        int row = idx >> 5, q = idx & 31;
        float4 v = *(const float4*)(x + (size_t)row * 128 + q * 4);
        *(u32*)(ax + (size_t)row * 256 + 128 + q * 4) = pack2(v.x, v.y);
        *(u32*)(ax + (size_t)row * 256 + 128 + q * 4 + 2) = pack2(v.z, v.w);
    } else if (bid < SCBLKS + XBLKS + 256) {
        int m = bid - SCBLKS - XBLKS;   // 0..255 output col
        int k = t;                       // reduction idx
        BT2[m * 256 + k] = f2b(k < 128 ? Wr2[k * 256 + m] : Wo2[(k - 128) * 256 + m]);
        BT3[m * 256 + k] = f2b(m < 128 ? Wr3[k * 128 + m] : Wo3[k * 128 + (m - 128)]);
        if (m < 128)
            BT1[m * 256 + k] = f2b(k < 128 ? Wr1[k * 128 + m] : Wo1[(k - 128) * 128 + m]);
        if (k == 0) bias3[m] = (m < 128) ? 0.f : br3[m - 128];
    } else {
        int g = (bid - SCBLKS - XBLKS - 256) * 256 + t;   // 0..767
        if (g <= GG) gn[g] = lower_bound_i(batch, NN, g);
    }
}

// ---------------- CSR pass 2 (512 threads/block; srcl in u16) ----------------

__global__ __launch_bounds__(512) void bfill_kernel(const u32* __restrict__ pairs,
                                                    const int* __restrict__ bcnt,
                                                    int* __restrict__ ofs,
                                                    u16* __restrict__ srcl) {
    __shared__ int sc[256];
    __shared__ int cnts[256];
    __shared__ int lcnt[256];
    __shared__ int lcur[256];
    __shared__ int lbuf[BCAP];
    int b = blockIdx.x, t = threadIdx.x;
    if (t < 256) {
        int c = (t < NB) ? bcnt[t] : 0;
        cnts[t] = c;
        sc[t] = c;
        lcnt[t] = 0;
    }
    __syncthreads();
    for (int off = 1; off < 256; off <<= 1) {
        int v = (t >= off && t < 256) ? sc[t - off] : 0;
        __syncthreads();
        if (t < 256) sc[t] += v;
        __syncthreads();
    }
    int base = sc[b] - cnts[b];
    int span = cnts[b];
    const u32* pp = pairs + (size_t)b * BSTRIDE;
    for (int j = t; j < span; j += 512) atomicAdd(&lcnt[pp[j] & 255u], 1);
    __syncthreads();
    int nc = 0;
    if (t < 256) {
        nc = lcnt[t];
        sc[t] = nc;
    }
    __syncthreads();
    for (int off = 1; off < 256; off <<= 1) {
        int v = (t >= off && t < 256) ? sc[t - off] : 0;
        __syncthreads();
        if (t < 256) sc[t] += v;
        __syncthreads();
    }
    if (t < 256) {
        int excl = sc[t] - nc;
        int node = b * 256 + t;
        if (node < NN) ofs[node] = base + excl;
        lcur[t] = excl;
    }
    if (b == 0 && t == 256) ofs[NN] = EE;
    __syncthreads();
    for (int j = t; j < span; j += 512) {
        u32 p = pp[j];
        int pos = atomicAdd(&lcur[p & 255u], 1);
        int src = (int)(p >> 8);
        if (pos < BCAP) lbuf[pos] = src;
        else srcl[base + pos] = (u16)src;
    }
    __syncthreads();
    int lim = span < BCAP ? span : BCAP;
    for (int j = t; j < lim; j += 512) srcl[base + j] = (u16)lbuf[j];
}

// ---------------- bf16 pull, row-major, wide-load, 16-edge unroll (R0 proven) ----

__global__ __launch_bounds__(256) void pull_bf_kernel(const u32* __restrict__ Xu,
                                                      const int* __restrict__ ofs,
                                                      const u16* __restrict__ srcl,
                                                      u32* __restrict__ outu) {
    int node = (blockIdx.x * 256 + threadIdx.x) >> 6;
    int lane = threadIdx.x & 63;
    int q = lane >> 4, l = lane & 15;
    int lo = ofs[node], hi = ofs[node + 1];
    float2 a0 = {0.f, 0.f}, a1 = {0.f, 0.f}, a2 = {0.f, 0.f}, a3 = {0.f, 0.f};
    int j = lo;
    for (; j + 15 < hi; j += 16) {
        int s0 = srcl[j + q], s1 = srcl[j + 4 + q];
        int s2 = srcl[j + 8 + q], s3 = srcl[j + 12 + q];
        uint4 v0 = *(const uint4*)(Xu + (size_t)s0 * 128 + l * 4);
        uint4 v1 = *(const uint4*)(Xu + (size_t)s1 * 128 + l * 4);
        uint4 v2 = *(const uint4*)(Xu + (size_t)s2 * 128 + l * 4);
        uint4 v3 = *(const uint4*)(Xu + (size_t)s3 * 128 + l * 4);
        acc2(a0, v0.x); acc2(a1, v0.y); acc2(a2, v0.z); acc2(a3, v0.w);
        acc2(a0, v1.x); acc2(a1, v1.y); acc2(a2, v1.z); acc2(a3, v1.w);
        acc2(a0, v2.x); acc2(a1, v2.y); acc2(a2, v2.z); acc2(a3, v2.w);
        acc2(a0, v3.x); acc2(a1, v3.y); acc2(a2, v3.z); acc2(a3, v3.w);
    }
    for (; j + 3 < hi; j += 4) {
        int s = srcl[j + q];
        uint4 v = *(const uint4*)(Xu + (size_t)s * 128 + l * 4);
        acc2(a0, v.x); acc2(a1, v.y); acc2(a2, v.z); acc2(a3, v.w);
    }
    if (j + q < hi) {
        int s = srcl[j + q];
        uint4 v = *(const uint4*)(Xu + (size_t)s * 128 + l * 4);
        acc2(a0, v.x); acc2(a1, v.y); acc2(a2, v.z); acc2(a3, v.w);
    }
    float acc[8] = {a0.x, a0.y, a1.x, a1.y, a2.x, a2.y, a3.x, a3.y};
#pragma unroll
    for (int i = 0; i < 8; ++i) {
        acc[i] += __shfl_xor(acc[i], 16, 64);
        acc[i] += __shfl_xor(acc[i], 32, 64);
    }
    if (q == 0) {
        uint4 r;
        r.x = pack2(acc[0], acc[1]);
        r.y = pack2(acc[2], acc[3]);
        r.z = pack2(acc[4], acc[5]);
        r.w = pack2(acc[6], acc[7]);
        *(uint4*)(outu + (size_t)node * 128 + l * 4) = r;
    }
}

// ---------------- bf16 MFMA GEMM: C = relu?(A @ BT^T + bias), K=256 ----------------

__global__ __launch_bounds__(256, 2) void gemm_bf_kernel(
    const u16* __restrict__ A, const u16* __restrict__ BT,
    const float* __restrict__ bias, u16* __restrict__ C,
    int ldc, int coloff, int relu) {
    __shared__ alignas(16) u16 As[128 * 32];
    __shared__ alignas(16) u16 Bs[128 * 32];
    const int t = threadIdx.x;
    const int lane = t & 63, wid = t >> 6;
    const int quad = lane >> 4, l16 = lane & 15;
    const int wm = wid >> 1, wn = wid & 1;
    const int row0 = blockIdx.y * 128, c0 = blockIdx.x * 128;

    frag_cd acc[4][4];
#pragma unroll
    for (int i = 0; i < 4; ++i)
#pragma unroll
        for (int j = 0; j < 4; ++j) acc[i][j] = (frag_cd)0.f;

    const int ca = t, cb = t + 256;
    const int ra = ca >> 2, oa = (ca & 3) * 8;
    const int rb = cb >> 2, ob = (cb & 3) * 8;
    const int garow = min(row0 + ra, NN - 1);
    const int gbrow = min(row0 + rb, NN - 1);
    const size_t gA1 = (size_t)garow * 256 + oa;
    const size_t gA2 = (size_t)gbrow * 256 + ob;
    const size_t gB1 = (size_t)(c0 + ra) * 256 + oa;
    const size_t gB2 = (size_t)(c0 + rb) * 256 + ob;

    for (int kk = 0; kk < 256; kk += 32) {
        __syncthreads();
        gl_lds16(A + gA1 + kk, &As[ca * 8]);
        gl_lds16(A + gA2 + kk, &As[cb * 8]);
        gl_lds16(BT + gB1 + kk, &Bs[ca * 8]);
        gl_lds16(BT + gB2 + kk, &Bs[cb * 8]);
        __syncthreads();

        frag_ab a[4], b[4];
#pragma unroll
        for (int mt = 0; mt < 4; ++mt)
            a[mt] = *(const frag_ab*)&As[(wm * 64 + mt * 16 + l16) * 32 + quad * 8];
#pragma unroll
        for (int nt = 0; nt < 4; ++nt)
            b[nt] = *(const frag_ab*)&Bs[(wn * 64 + nt * 16 + l16) * 32 + quad * 8];
#pragma unroll
        for (int mt = 0; mt < 4; ++mt)
#pragma unroll
            for (int nt = 0; nt < 4; ++nt)
                acc[mt][nt] = __builtin_amdgcn_mfma_f32_16x16x32_bf16(
                    a[mt], b[nt], acc[mt][nt], 0, 0, 0);
    }

#pragma unroll
    for (int nt = 0; nt < 4; ++nt) {
        int col = c0 + wn * 64 + nt * 16 + l16;
        float bv = bias[col];
#pragma unroll
        for (int mt = 0; mt < 4; ++mt) {
#pragma unroll
            for (int r = 0; r < 4; ++r) {
                int row = row0 + wm * 64 + mt * 16 + quad * 4 + r;
                if (row < NN) {
                    float v = acc[mt][nt][r] + bv;
                    if (relu) v = fmaxf(v, 0.f);
                    C[(size_t)row * ldc + coloff + col] = f2b(v);
                }
            }
        }
    }
}

// ---------------- fused GEMM2+GEMM3, barrier-light ---------------------------------
// Stage 1: h2 = relu(A@BT2^T+br2); A- and B-frags direct from global
// (line-coalesced: 16 rows x 64B per frag-load), acc[2][4][4] covers both
// col-halves in one kk loop. Park h2 in XOR-swizzled Hs (64 KB). One barrier.
// Stage 2: t3o3 = Hs@BT3^T+bias3; A from LDS, B direct. No loop barriers.
// Epilogue: repack C via Hs (XOR moves whole 16B groups) -> dwordx4 stores.

__global__ __launch_bounds__(256, 2) void gemm23_kernel(
    const u16* __restrict__ A, const u16* __restrict__ BT2,
    const float* __restrict__ br2, const u16* __restrict__ BT3,
    const float* __restrict__ bias3, u16* __restrict__ C) {
    __shared__ alignas(16) u16 Hs[128 * 256];
    const int t = threadIdx.x;
    const int lane = t & 63, wid = t >> 6;
    const int quad = lane >> 4, l16 = lane & 15;
    const int wm = wid >> 1, wn = wid & 1;
    const int row0 = blockIdx.x * 128;

    size_t aoff[4];
#pragma unroll
    for (int mt = 0; mt < 4; ++mt) {
        int r = min(row0 + wm * 64 + mt * 16 + l16, NN - 1);
        aoff[mt] = (size_t)r * 256 + quad * 8;
    }
    size_t boff[2][4];
#pragma unroll
    for (int nb = 0; nb < 2; ++nb)
#pragma unroll
        for (int nt = 0; nt < 4; ++nt)
            boff[nb][nt] = (size_t)(nb * 128 + wn * 64 + nt * 16 + l16) * 256 + quad * 8;

    frag_cd acc[2][4][4];
#pragma unroll
    for (int nb = 0; nb < 2; ++nb)
#pragma unroll
        for (int i = 0; i < 4; ++i)
#pragma unroll
            for (int j = 0; j < 4; ++j) acc[nb][i][j] = (frag_cd)0.f;

    // ---- stage 1 ----
    for (int kk = 0; kk < 256; kk += 32) {
        frag_ab a[4], b[2][4];
#pragma unroll
        for (int mt = 0; mt < 4; ++mt)
            a[mt] = *(const frag_ab*)(A + aoff[mt] + kk);
#pragma unroll
        for (int nb = 0; nb < 2; ++nb)
#pragma unroll
            for (int nt = 0; nt < 4; ++nt)
                b[nb][nt] = *(const frag_ab*)(BT2 + boff[nb][nt] + kk);
#pragma unroll
        for (int nb = 0; nb < 2; ++nb)
#pragma unroll
            for (int mt = 0; mt < 4; ++mt)
#pragma unroll
                for (int nt = 0; nt < 4; ++nt)
                    acc[nb][mt][nt] = __builtin_amdgcn_mfma_f32_16x16x32_bf16(
                        a[mt], b[nb][nt], acc[nb][mt][nt], 0, 0, 0);
    }
    // park h2 in swizzled LDS (bias + relu + bf16 round)
#pragma unroll
    for (int nb = 0; nb < 2; ++nb)
#pragma unroll
        for (int nt = 0; nt < 4; ++nt) {
            int col = nb * 128 + wn * 64 + nt * 16 + l16;
            float bv = br2[col];
#pragma unroll
            for (int mt = 0; mt < 4; ++mt)
#pragma unroll
                for (int r = 0; r < 4; ++r) {
                    int lr = wm * 64 + mt * 16 + quad * 4 + r;
                    float v = fmaxf(acc[nb][mt][nt][r] + bv, 0.f);
                    Hs[(lr * 256 + col) ^ ((lr & 7) << 3)] = f2b(v);
                }
        }
    __syncthreads();

    // ---- stage 2 ----
    int hrow[4];
#pragma unroll
    for (int mt = 0; mt < 4; ++mt) hrow[mt] = wm * 64 + mt * 16 + l16;
#pragma unroll
    for (int nb = 0; nb < 2; ++nb)
#pragma unroll
        for (int i = 0; i < 4; ++i)
#pragma unroll
            for (int j = 0; j < 4; ++j) acc[nb][i][j] = (frag_cd)0.f;
    for (int kk = 0; kk < 256; kk += 32) {
        frag_ab a[4], b[2][4];
#pragma unroll
        for (int mt = 0; mt < 4; ++mt)
            a[mt] = *(const frag_ab*)&Hs[(hrow[mt] * 256 + kk + quad * 8) ^
                                         ((hrow[mt] & 7) << 3)];
#pragma unroll
        for (int nb = 0; nb < 2; ++nb)
#pragma unroll
            for (int nt = 0; nt < 4; ++nt)
                b[nb][nt] = *(const frag_ab*)(BT3 + boff[nb][nt] + kk);
#pragma unroll
        for (int nb = 0; nb < 2; ++nb)
#pragma unroll
            for (int mt = 0; mt < 4; ++mt)
#pragma unroll
                for (int nt = 0; nt < 4; ++nt)
                    acc[nb][mt][nt] = __builtin_amdgcn_mfma_f32_16x16x32_bf16(
                        a[mt], b[nb][nt], acc[nb][mt][nt], 0, 0, 0);
    }
    __syncthreads();   // all Hs reads complete before overwrite

    // ---- epilogue: repack C tile into Hs, then coalesced store ----
#pragma unroll
    for (int nb = 0; nb < 2; ++nb)
#pragma unroll
        for (int nt = 0; nt < 4; ++nt) {
            int col = nb * 128 + wn * 64 + nt * 16 + l16;
            float bv = bias3[col];
#pragma unroll
            for (int mt = 0; mt < 4; ++mt)
#pragma unroll
                for (int r = 0; r < 4; ++r) {
                    int lr = wm * 64 + mt * 16 + quad * 4 + r;
                    Hs[(lr * 256 + col) ^ ((lr & 7) << 3)] = f2b(acc[nb][mt][nt][r] + bv);
                }
        }
    __syncthreads();
    const uint4* Hs128 = (const uint4*)Hs;
#pragma unroll
    for (int it = 0; it < 16; ++it) {
        int row = it * 8 + (t >> 5);
        int grp = t & 31;
        uint4 v = Hs128[row * 32 + (grp ^ (row & 7))];
        int grow = row0 + row;
        if (grow < NN)
            *(uint4*)(C + (size_t)grow * 256 + grp * 8) = v;
    }
}

// ---------------- pool3_seg: per-(graph,segment) gather partials ------------------

__global__ __launch_bounds__(256) void pool3_seg_kernel(
    const u32* __restrict__ Tu, const int* __restrict__ ofs,
    const u16* __restrict__ srcl, const int* __restrict__ gn,
    float* __restrict__ psum) {
    __shared__ float red[4][128];
    __shared__ float po[2][128];
    int gb = blockIdx.x;
    int g = gb >> 3, s = gb & 7;
    int t = threadIdx.x;
    int w = t >> 6, lane = t & 63;
    int q = lane >> 4, l = lane & 15;
    int n_lo = gn[g], n_hi = gn[g + 1];
    int glo = ofs[n_lo], ghi = ofs[n_hi];
    int len = ghi - glo;
    int s_lo = glo + (int)(((long long)len * s) >> 3);
    int s_hi = glo + (int)(((long long)len * (s + 1)) >> 3);
    int slen = s_hi - s_lo;
    int wlo = s_lo + ((slen * w) >> 2);
    int whi = s_lo + ((slen * (w + 1)) >> 2);

    float2 a0 = {0.f, 0.f}, a1 = {0.f, 0.f}, a2 = {0.f, 0.f}, a3 = {0.f, 0.f};
    int j = wlo;
    for (; j + 15 < whi; j += 16) {
        int s0 = srcl[j + q], s1 = srcl[j + 4 + q];
        int s2 = srcl[j + 8 + q], s3 = srcl[j + 12 + q];
        uint4 v0 = *(const uint4*)(Tu + (size_t)s0 * 128 + l * 4);
        uint4 v1 = *(const uint4*)(Tu + (size_t)s1 * 128 + l * 4);
        uint4 v2 = *(const uint4*)(Tu + (size_t)s2 * 128 + l * 4);
        uint4 v3 = *(const uint4*)(Tu + (size_t)s3 * 128 + l * 4);
        acc2(a0, v0.x); acc2(a1, v0.y); acc2(a2, v0.z); acc2(a3, v0.w);
        acc2(a0, v1.x); acc2(a1, v1.y); acc2(a2, v1.z); acc2(a3, v1.w);
        acc2(a0, v2.x); acc2(a1, v2.y); acc2(a2, v2.z); acc2(a3, v2.w);
        acc2(a0, v3.x); acc2(a1, v3.y); acc2(a2, v3.z); acc2(a3, v3.w);
    }
    for (; j + 3 < whi; j += 4) {
        int sv = srcl[j + q];
        uint4 v = *(const uint4*)(Tu + (size_t)sv * 128 + l * 4);
        acc2(a0, v.x); acc2(a1, v.y); acc2(a2, v.z); acc2(a3, v.w);
    }
    if (j + q < whi) {
        int sv = srcl[j + q];
        uint4 v = *(const uint4*)(Tu + (size_t)sv * 128 + l * 4);
        acc2(a0, v.x); acc2(a1, v.y); acc2(a2, v.z); acc2(a3, v.w);
    }
    float acc[8] = {a0.x, a0.y, a1.x, a1.y, a2.x, a2.y, a3.x, a3.y};
#pragma unroll
    for (int i = 0; i < 8; ++i) {
        acc[i] += __shfl_xor(acc[i], 16, 64);
        acc[i] += __shfl_xor(acc[i], 32, 64);
    }
    if (q == 0) {
#pragma unroll
        for (int i = 0; i < 8; ++i) red[w][l * 8 + i] = acc[i];
    }
    // o3 partial: 16 row streams (8 segs x 2 rowgroups), rows step 16
    float so = 0.f;
    int ch = t & 127, rg = t >> 7;
    for (int r = n_lo + s * 2 + rg; r < n_hi; r += 16)
        so += b2f(Tu[(size_t)r * 128 + 64 + (ch >> 1)], ch & 1);
    po[rg][ch] = so;
    __syncthreads();
    if (t < 128) {
        float v = red[0][t] + red[1][t] + red[2][t] + red[3][t] + po[0][t] + po[1][t];
        psum[((size_t)g * PSEG + s) * 128 + t] = v;
    }
}

// ---------------- per-graph head: reduce 8 partials, mean, MLP ---------------------

__global__ __launch_bounds__(128) void head_kernel(
    const float* __restrict__ psum, const int* __restrict__ gn,
    const float* __restrict__ W1, const float* __restrict__ b1,
    const float* __restrict__ W2, const float* __restrict__ b2,
    float* __restrict__ out) {
    __shared__ float p[128];
    __shared__ float hid[40];
    int g = blockIdx.x, t = threadIdx.x;
    int cnt = gn[g + 1] - gn[g];
    float sv = 0.f;
#pragma unroll
    for (int k = 0; k < PSEG; ++k) sv += psum[((size_t)g * PSEG + k) * 128 + t];
    p[t] = sv / fmaxf((float)cnt, 1.f);
    __syncthreads();
    if (t < 40) {
        float v = b1[t];
        for (int k = 0; k < 128; ++k) v += p[k] * W1[k * 40 + t];
        hid[t] = v;
    }
    __syncthreads();
    if (t < 10) {
        float v = b2[t];
        for (int j = 0; j < 40; ++j) v += hid[j] * W2[j * 10 + t];
        out[g * 10 + t] = v;
    }
}

// ---------------- launch ----------------

extern "C" void kernel_launch(void* const* d_in, const int* in_sizes, int n_in,
                              void* d_out, int out_size, void* d_ws, size_t ws_size,
                              hipStream_t stream) {
    const float* x   = (const float*)d_in[0];
    const int* ei    = (const int*)d_in[1];
    const int* batch = (const int*)d_in[2];
    const float* Wr1 = (const float*)d_in[3];
    const float* br1 = (const float*)d_in[4];
    const float* Wo1 = (const float*)d_in[5];
    const float* Wr2 = (const float*)d_in[6];
    const float* br2 = (const float*)d_in[7];
    const float* Wo2 = (const float*)d_in[8];
    const float* Wr3 = (const float*)d_in[9];
    const float* br3 = (const float*)d_in[10];
    const float* Wo3 = (const float*)d_in[11];
    const float* W1  = (const float*)d_in[12];
    const float* b1  = (const float*)d_in[13];
    const float* W2  = (const float*)d_in[14];
    const float* b2  = (const float*)d_in[15];
    float* out = (float*)d_out;

    char* ws = (char*)d_ws;
    size_t off = 0;
    auto alloc = [&](size_t bytes) {
        void* p = ws + off;
        off += (bytes + 255) & ~(size_t)255;
        return p;
    };
    int* ofs      = (int*)alloc((NN + 1) * sizeof(int));
    int* bcnt     = (int*)alloc(256 * sizeof(int));
    int* gn       = (int*)alloc((GG + 1) * sizeof(int));
    u16* srcl     = (u16*)alloc((size_t)EE * 2);
    u16* ax       = (u16*)alloc((size_t)NN * 256 * 2);   // cols 0-127 agg, 128-255 x_bf
    u16* ah1      = (u16*)alloc((size_t)NN * 256 * 2);   // cols 0-127 agg(h1), 128-255 h1
    u16* t3o3     = (u16*)alloc((size_t)NN * 256 * 2);   // cols 0-127 t3, 128-255 o3
    float* psum   = (float*)alloc((size_t)GG * PSEG * 128 * sizeof(float));
    u16* BT1      = (u16*)alloc(128 * 256 * 2);
    u16* BT2      = (u16*)alloc(256 * 256 * 2);
    u16* BT3      = (u16*)alloc(256 * 256 * 2);
    float* bias3  = (float*)alloc(256 * sizeof(float));
    // pairs (12.85 MB) overlays t3o3 (25.6 MB): pairs lifetime ends at bfill,
    // t3o3 first written at gemm23.
    u32* pairs = (u32*)t3o3;

    hipMemsetAsync(bcnt, 0, 256 * sizeof(int), stream);

    // CSR pass 1 + x->bf16 + weight prep + graph node-ranges (fused ranges)
    bscatter_prep_kernel<<<SCBLKS + XBLKS + 256 + 3, 256, 0, stream>>>(
        ei, bcnt, pairs, x, ax, Wr1, Wo1, Wr2, Wo2, Wr3, Wo3, br3,
        BT1, BT2, BT3, bias3, batch, gn);
    // CSR pass 2
    bfill_kernel<<<NB, 512, 0, stream>>>(pairs, bcnt, ofs, srcl);

    // conv1
    pull_bf_kernel<<<NN * 64 / 256, 256, 0, stream>>>((const u32*)ax + 64, ofs, srcl, (u32*)ax);
    gemm_bf_kernel<<<dim3(1, 391), 256, 0, stream>>>(ax, BT1, br1, ah1, 256, 128, 1);
    // conv2
    pull_bf_kernel<<<NN * 64 / 256, 256, 0, stream>>>((const u32*)ah1 + 64, ofs, srcl, (u32*)ah1);
    // conv2 GEMM + conv3 GEMM fused: t3o3 = relu(ah1@BT2^T+br2) @ BT3^T + bias3
    gemm23_kernel<<<391, 256, 0, stream>>>(ah1, BT2, br2, BT3, bias3, t3o3);

    // fused h3-aggregation + pool partials (per graph-segment), then head
    pool3_seg_kernel<<<GG * PSEG, 256, 0, stream>>>((const u32*)t3o3, ofs, srcl, gn, psum);
    head_kernel<<<GG, 128, 0, stream>>>(psum, gn, W1, b1, W2, b2, out);
}

// Round 7
// 339.970 us; speedup vs baseline: 1.1040x; 1.1040x over previous
//
#include <hip/hip_runtime.h>
#include <hip/hip_bf16.h>
#include <cstddef>

#define NN 50000
#define EE 1600000
#define GG 512
#define NB 196        // ceil(NN/256) buckets of 256 nodes
#define BSTRIDE 16384 // fixed pairs-region capacity per bucket (max span ~8600)
#define BCAP 10240    // LDS staging per bucket
#define XBLKS 6250    // NN*32/256 x-convert blocks
#define SCBLKS 782    // ceil(EE/2048) bscatter blocks
#define PSEG 8        // edge segments per graph in pool3_seg

typedef unsigned int u32;
typedef unsigned short u16;
typedef __attribute__((ext_vector_type(8))) short frag_ab;   // 8 bf16 = 4 VGPRs
typedef __attribute__((ext_vector_type(4))) float frag_cd;   // 4 fp32 acc

__device__ __forceinline__ void gl_lds16(const void* g, void* l) {
    __builtin_amdgcn_global_load_lds(
        (const __attribute__((address_space(1))) u32*)g,
        (__attribute__((address_space(3))) u32*)l, 16, 0, 0);
}
__device__ __forceinline__ float b2f_lo(u32 v) { return __uint_as_float(v << 16); }
__device__ __forceinline__ float b2f_hi(u32 v) { return __uint_as_float(v & 0xffff0000u); }
__device__ __forceinline__ float b2f(u32 v, int odd) { return odd ? b2f_hi(v) : b2f_lo(v); }
__device__ __forceinline__ u16 f2b(float x) {
    __hip_bfloat16 h = __float2bfloat16(x);
    return *(u16*)&h;
}
__device__ __forceinline__ u32 pack2(float lo, float hi) {
    return ((u32)f2b(hi) << 16) | f2b(lo);
}
__device__ __forceinline__ void acc2(float2& a, u32 v) {
    a.x += b2f_lo(v);
    a.y += b2f_hi(v);
}

__device__ inline int lower_bound_i(const int* a, int n, int v) {
    int lo = 0, hi = n;
    while (lo < hi) {
        int m = (lo + hi) >> 1;
        if (a[m] < v) lo = m + 1; else hi = m;
    }
    return lo;
}

// gemm23: R5's staged structure (gl_lds + LDS frags, proven) with M-tile 64:
// grid 782 ~= 3 blocks/CU, LDS 52 KB (As 4 + Bs 16 + Hs 32) -> 3 resident
// blocks/CU so barrier drains overlap across blocks (m114). One kk loop
// computes all 256 cols (acc[16]/wave); stage-2 A-frags read own-wave Hs rows.

// ---------------- fused: edge bucket-scatter + x->bf16 + weight prep + gn ----------

__global__ __launch_bounds__(256) void bscatter_prep_kernel(
    const int* __restrict__ ei, int* __restrict__ bcnt, u32* __restrict__ pairs,
    const float* __restrict__ x, u16* __restrict__ ax,
    const float* __restrict__ Wr1, const float* __restrict__ Wo1,
    const float* __restrict__ Wr2, const float* __restrict__ Wo2,
    const float* __restrict__ Wr3, const float* __restrict__ Wo3,
    const float* __restrict__ br3,
    u16* __restrict__ BT1, u16* __restrict__ BT2, u16* __restrict__ BT3,
    float* __restrict__ bias3, const int* __restrict__ batch,
    int* __restrict__ gn) {
    __shared__ int lcnt[NB];
    __shared__ int lbase[NB];
    __shared__ unsigned short lpos[2048];
    int bid = blockIdx.x, t = threadIdx.x;
    if (bid < SCBLKS) {
        int e0 = bid * 2048;
        u32 pk[8];   // packed (src<<8)|(dst&255) stashed across phases
        int bk[8];
        for (int i = t; i < NB; i += 256) lcnt[i] = 0;
        __syncthreads();
#pragma unroll
        for (int i = 0; i < 8; ++i) {
            int e = e0 + i * 256 + t;
            if (e < EE) {
                int dst = ei[EE + e], src = ei[e];
                int b = dst >> 8;
                bk[i] = b;
                pk[i] = ((u32)src << 8) | (u32)(dst & 255);
                lpos[i * 256 + t] = (unsigned short)atomicAdd(&lcnt[b], 1);
            } else bk[i] = -1;
        }
        __syncthreads();
        for (int i = t; i < NB; i += 256) lbase[i] = atomicAdd(&bcnt[i], lcnt[i]);
        __syncthreads();
#pragma unroll
        for (int i = 0; i < 8; ++i) {
            if (bk[i] >= 0) {
                int pos = lbase[bk[i]] + (int)lpos[i * 256 + t];
                pairs[(size_t)bk[i] * BSTRIDE + pos] = pk[i];
            }
        }
    } else if (bid < SCBLKS + XBLKS) {
        int idx = (bid - SCBLKS) * 256 + t;
        int row = idx >> 5, q = idx & 31;
        float4 v = *(const float4*)(x + (size_t)row * 128 + q * 4);
        *(u32*)(ax + (size_t)row * 256 + 128 + q * 4) = pack2(v.x, v.y);
        *(u32*)(ax + (size_t)row * 256 + 128 + q * 4 + 2) = pack2(v.z, v.w);
    } else if (bid < SCBLKS + XBLKS + 256) {
        int m = bid - SCBLKS - XBLKS;   // 0..255 output col
        int k = t;                       // reduction idx
        BT2[m * 256 + k] = f2b(k < 128 ? Wr2[k * 256 + m] : Wo2[(k - 128) * 256 + m]);
        BT3[m * 256 + k] = f2b(m < 128 ? Wr3[k * 128 + m] : Wo3[k * 128 + (m - 128)]);
        if (m < 128)
            BT1[m * 256 + k] = f2b(k < 128 ? Wr1[k * 128 + m] : Wo1[(k - 128) * 128 + m]);
        if (k == 0) bias3[m] = (m < 128) ? 0.f : br3[m - 128];
    } else {
        int g = (bid - SCBLKS - XBLKS - 256) * 256 + t;   // 0..767
        if (g <= GG) gn[g] = lower_bound_i(batch, NN, g);
    }
}

// ---------------- CSR pass 2 (512 threads/block; srcl in u16) ----------------

__global__ __launch_bounds__(512) void bfill_kernel(const u32* __restrict__ pairs,
                                                    const int* __restrict__ bcnt,
                                                    int* __restrict__ ofs,
                                                    u16* __restrict__ srcl) {
    __shared__ int sc[256];
    __shared__ int cnts[256];
    __shared__ int lcnt[256];
    __shared__ int lcur[256];
    __shared__ int lbuf[BCAP];
    int b = blockIdx.x, t = threadIdx.x;
    if (t < 256) {
        int c = (t < NB) ? bcnt[t] : 0;
        cnts[t] = c;
        sc[t] = c;
        lcnt[t] = 0;
    }
    __syncthreads();
    for (int off = 1; off < 256; off <<= 1) {
        int v = (t >= off && t < 256) ? sc[t - off] : 0;
        __syncthreads();
        if (t < 256) sc[t] += v;
        __syncthreads();
    }
    int base = sc[b] - cnts[b];
    int span = cnts[b];
    const u32* pp = pairs + (size_t)b * BSTRIDE;
    for (int j = t; j < span; j += 512) atomicAdd(&lcnt[pp[j] & 255u], 1);
    __syncthreads();
    int nc = 0;
    if (t < 256) {
        nc = lcnt[t];
        sc[t] = nc;
    }
    __syncthreads();
    for (int off = 1; off < 256; off <<= 1) {
        int v = (t >= off && t < 256) ? sc[t - off] : 0;
        __syncthreads();
        if (t < 256) sc[t] += v;
        __syncthreads();
    }
    if (t < 256) {
        int excl = sc[t] - nc;
        int node = b * 256 + t;
        if (node < NN) ofs[node] = base + excl;
        lcur[t] = excl;
    }
    if (b == 0 && t == 256) ofs[NN] = EE;
    __syncthreads();
    for (int j = t; j < span; j += 512) {
        u32 p = pp[j];
        int pos = atomicAdd(&lcur[p & 255u], 1);
        int src = (int)(p >> 8);
        if (pos < BCAP) lbuf[pos] = src;
        else srcl[base + pos] = (u16)src;
    }
    __syncthreads();
    int lim = span < BCAP ? span : BCAP;
    for (int j = t; j < lim; j += 512) srcl[base + j] = (u16)lbuf[j];
}

// ---------------- bf16 pull, row-major, wide-load, 16-edge unroll (R0 proven) ----

__global__ __launch_bounds__(256) void pull_bf_kernel(const u32* __restrict__ Xu,
                                                      const int* __restrict__ ofs,
                                                      const u16* __restrict__ srcl,
                                                      u32* __restrict__ outu) {
    int node = (blockIdx.x * 256 + threadIdx.x) >> 6;
    int lane = threadIdx.x & 63;
    int q = lane >> 4, l = lane & 15;
    int lo = ofs[node], hi = ofs[node + 1];
    float2 a0 = {0.f, 0.f}, a1 = {0.f, 0.f}, a2 = {0.f, 0.f}, a3 = {0.f, 0.f};
    int j = lo;
    for (; j + 15 < hi; j += 16) {
        int s0 = srcl[j + q], s1 = srcl[j + 4 + q];
        int s2 = srcl[j + 8 + q], s3 = srcl[j + 12 + q];
        uint4 v0 = *(const uint4*)(Xu + (size_t)s0 * 128 + l * 4);
        uint4 v1 = *(const uint4*)(Xu + (size_t)s1 * 128 + l * 4);
        uint4 v2 = *(const uint4*)(Xu + (size_t)s2 * 128 + l * 4);
        uint4 v3 = *(const uint4*)(Xu + (size_t)s3 * 128 + l * 4);
        acc2(a0, v0.x); acc2(a1, v0.y); acc2(a2, v0.z); acc2(a3, v0.w);
        acc2(a0, v1.x); acc2(a1, v1.y); acc2(a2, v1.z); acc2(a3, v1.w);
        acc2(a0, v2.x); acc2(a1, v2.y); acc2(a2, v2.z); acc2(a3, v2.w);
        acc2(a0, v3.x); acc2(a1, v3.y); acc2(a2, v3.z); acc2(a3, v3.w);
    }
    for (; j + 3 < hi; j += 4) {
        int s = srcl[j + q];
        uint4 v = *(const uint4*)(Xu + (size_t)s * 128 + l * 4);
        acc2(a0, v.x); acc2(a1, v.y); acc2(a2, v.z); acc2(a3, v.w);
    }
    if (j + q < hi) {
        int s = srcl[j + q];
        uint4 v = *(const uint4*)(Xu + (size_t)s * 128 + l * 4);
        acc2(a0, v.x); acc2(a1, v.y); acc2(a2, v.z); acc2(a3, v.w);
    }
    float acc[8] = {a0.x, a0.y, a1.x, a1.y, a2.x, a2.y, a3.x, a3.y};
#pragma unroll
    for (int i = 0; i < 8; ++i) {
        acc[i] += __shfl_xor(acc[i], 16, 64);
        acc[i] += __shfl_xor(acc[i], 32, 64);
    }
    if (q == 0) {
        uint4 r;
        r.x = pack2(acc[0], acc[1]);
        r.y = pack2(acc[2], acc[3]);
        r.z = pack2(acc[4], acc[5]);
        r.w = pack2(acc[6], acc[7]);
        *(uint4*)(outu + (size_t)node * 128 + l * 4) = r;
    }
}

// ---------------- bf16 MFMA GEMM: C = relu?(A @ BT^T + bias), K=256 ----------------

__global__ __launch_bounds__(256, 2) void gemm_bf_kernel(
    const u16* __restrict__ A, const u16* __restrict__ BT,
    const float* __restrict__ bias, u16* __restrict__ C,
    int ldc, int coloff, int relu) {
    __shared__ alignas(16) u16 As[128 * 32];
    __shared__ alignas(16) u16 Bs[128 * 32];
    const int t = threadIdx.x;
    const int lane = t & 63, wid = t >> 6;
    const int quad = lane >> 4, l16 = lane & 15;
    const int wm = wid >> 1, wn = wid & 1;
    const int row0 = blockIdx.y * 128, c0 = blockIdx.x * 128;

    frag_cd acc[4][4];
#pragma unroll
    for (int i = 0; i < 4; ++i)
#pragma unroll
        for (int j = 0; j < 4; ++j) acc[i][j] = (frag_cd)0.f;

    const int ca = t, cb = t + 256;
    const int ra = ca >> 2, oa = (ca & 3) * 8;
    const int rb = cb >> 2, ob = (cb & 3) * 8;
    const int garow = min(row0 + ra, NN - 1);
    const int gbrow = min(row0 + rb, NN - 1);
    const size_t gA1 = (size_t)garow * 256 + oa;
    const size_t gA2 = (size_t)gbrow * 256 + ob;
    const size_t gB1 = (size_t)(c0 + ra) * 256 + oa;
    const size_t gB2 = (size_t)(c0 + rb) * 256 + ob;

    for (int kk = 0; kk < 256; kk += 32) {
        __syncthreads();
        gl_lds16(A + gA1 + kk, &As[ca * 8]);
        gl_lds16(A + gA2 + kk, &As[cb * 8]);
        gl_lds16(BT + gB1 + kk, &Bs[ca * 8]);
        gl_lds16(BT + gB2 + kk, &Bs[cb * 8]);
        __syncthreads();

        frag_ab a[4], b[4];
#pragma unroll
        for (int mt = 0; mt < 4; ++mt)
            a[mt] = *(const frag_ab*)&As[(wm * 64 + mt * 16 + l16) * 32 + quad * 8];
#pragma unroll
        for (int nt = 0; nt < 4; ++nt)
            b[nt] = *(const frag_ab*)&Bs[(wn * 64 + nt * 16 + l16) * 32 + quad * 8];
#pragma unroll
        for (int mt = 0; mt < 4; ++mt)
#pragma unroll
            for (int nt = 0; nt < 4; ++nt)
                acc[mt][nt] = __builtin_amdgcn_mfma_f32_16x16x32_bf16(
                    a[mt], b[nt], acc[mt][nt], 0, 0, 0);
    }

#pragma unroll
    for (int nt = 0; nt < 4; ++nt) {
        int col = c0 + wn * 64 + nt * 16 + l16;
        float bv = bias[col];
#pragma unroll
        for (int mt = 0; mt < 4; ++mt) {
#pragma unroll
            for (int r = 0; r < 4; ++r) {
                int row = row0 + wm * 64 + mt * 16 + quad * 4 + r;
                if (row < NN) {
                    float v = acc[mt][nt][r] + bv;
                    if (relu) v = fmaxf(v, 0.f);
                    C[(size_t)row * ldc + coloff + col] = f2b(v);
                }
            }
        }
    }
}

// ---------------- fused GEMM2+GEMM3, M-tile 64, 3 blocks/CU ------------------------
// Stage 1: h2 = relu(A@BT2^T+br2), gl_lds-staged As(64x32)+Bs(256x32), one kk
// loop covers all cols (acc[16]/wave, wave w owns rows w*16..w*16+15).
// Park h2 in XOR-swizzled Hs (32 KB). Stage 2: t3o3 = Hs@BT3^T+bias3, A-frags
// from own-wave Hs rows (no cross-wave dep), Bs restaged per kk. Epilogue:
// repack through Hs -> coalesced dwordx4 stores.

__global__ __launch_bounds__(256, 3) void gemm23_kernel(
    const u16* __restrict__ A, const u16* __restrict__ BT2,
    const float* __restrict__ br2, const u16* __restrict__ BT3,
    const float* __restrict__ bias3, u16* __restrict__ C) {
    __shared__ alignas(16) u16 As[64 * 32];    // 4 KB
    __shared__ alignas(16) u16 Bs[256 * 32];   // 16 KB
    __shared__ alignas(16) u16 Hs[64 * 256];   // 32 KB
    const int t = threadIdx.x;
    const int lane = t & 63, w = t >> 6;
    const int quad = lane >> 4, l16 = lane & 15;
    const int row0 = blockIdx.x * 64;

    const int ra = t >> 2, oa = (t & 3) * 8;
    const int garow = min(row0 + ra, NN - 1);
    const size_t gA = (size_t)garow * 256 + oa;
    size_t gB[4];
#pragma unroll
    for (int i = 0; i < 4; ++i) {
        int cbi = i * 256 + t;
        gB[i] = (size_t)(cbi >> 2) * 256 + (cbi & 3) * 8;
    }

    frag_cd acc[16];
#pragma unroll
    for (int i = 0; i < 16; ++i) acc[i] = (frag_cd)0.f;

    // ---- stage 1 ----
    for (int kk = 0; kk < 256; kk += 32) {
        __syncthreads();
        gl_lds16(A + gA + kk, &As[t * 8]);
#pragma unroll
        for (int i = 0; i < 4; ++i)
            gl_lds16(BT2 + gB[i] + kk, &Bs[(i * 256 + t) * 8]);
        __syncthreads();
        frag_ab a = *(const frag_ab*)&As[(w * 16 + l16) * 32 + quad * 8];
#pragma unroll
        for (int nt = 0; nt < 16; ++nt) {
            frag_ab b = *(const frag_ab*)&Bs[(nt * 16 + l16) * 32 + quad * 8];
            acc[nt] = __builtin_amdgcn_mfma_f32_16x16x32_bf16(a, b, acc[nt], 0, 0, 0);
        }
    }
    // park h2 (own-wave rows) in swizzled Hs (bias + relu + bf16 round)
#pragma unroll
    for (int nt = 0; nt < 16; ++nt) {
        int col = nt * 16 + l16;
        float bv = br2[col];
#pragma unroll
        for (int r = 0; r < 4; ++r) {
            int lr = w * 16 + quad * 4 + r;
            float v = fmaxf(acc[nt][r] + bv, 0.f);
            Hs[(lr * 256 + col) ^ ((lr & 7) << 3)] = f2b(v);
        }
    }

    // ---- stage 2 (A from own-wave Hs rows; in-wave ds dependency only) ----
#pragma unroll
    for (int i = 0; i < 16; ++i) acc[i] = (frag_cd)0.f;
    const int hrow = w * 16 + l16;
    for (int kk = 0; kk < 256; kk += 32) {
        __syncthreads();   // all waves done reading Bs before restage
#pragma unroll
        for (int i = 0; i < 4; ++i)
            gl_lds16(BT3 + gB[i] + kk, &Bs[(i * 256 + t) * 8]);
        __syncthreads();
        frag_ab a = *(const frag_ab*)&Hs[(hrow * 256 + kk + quad * 8) ^
                                         ((hrow & 7) << 3)];
#pragma unroll
        for (int nt = 0; nt < 16; ++nt) {
            frag_ab b = *(const frag_ab*)&Bs[(nt * 16 + l16) * 32 + quad * 8];
            acc[nt] = __builtin_amdgcn_mfma_f32_16x16x32_bf16(a, b, acc[nt], 0, 0, 0);
        }
    }

    // ---- epilogue: repack C tile into Hs (own-wave rows), coalesced store ----
#pragma unroll
    for (int nt = 0; nt < 16; ++nt) {
        int col = nt * 16 + l16;
        float bv = bias3[col];
#pragma unroll
        for (int r = 0; r < 4; ++r) {
            int lr = w * 16 + quad * 4 + r;
            Hs[(lr * 256 + col) ^ ((lr & 7) << 3)] = f2b(acc[nt][r] + bv);
        }
    }
    __syncthreads();
    const uint4* Hs128 = (const uint4*)Hs;
#pragma unroll
    for (int it = 0; it < 8; ++it) {
        int row = it * 8 + (t >> 5);
        int grp = t & 31;
        uint4 v = Hs128[row * 32 + (grp ^ (row & 7))];
        int grow = row0 + row;
        if (grow < NN)
            *(uint4*)(C + (size_t)grow * 256 + grp * 8) = v;
    }
}

// ---------------- pool3_seg: per-(graph,segment) gather partials ------------------

__global__ __launch_bounds__(256) void pool3_seg_kernel(
    const u32* __restrict__ Tu, const int* __restrict__ ofs,
    const u16* __restrict__ srcl, const int* __restrict__ gn,
    float* __restrict__ psum) {
    __shared__ float red[4][128];
    __shared__ float po[2][128];
    int gb = blockIdx.x;
    int g = gb >> 3, s = gb & 7;
    int t = threadIdx.x;
    int w = t >> 6, lane = t & 63;
    int q = lane >> 4, l = lane & 15;
    int n_lo = gn[g], n_hi = gn[g + 1];
    int glo = ofs[n_lo], ghi = ofs[n_hi];
    int len = ghi - glo;
    int s_lo = glo + (int)(((long long)len * s) >> 3);
    int s_hi = glo + (int)(((long long)len * (s + 1)) >> 3);
    int slen = s_hi - s_lo;
    int wlo = s_lo + ((slen * w) >> 2);
    int whi = s_lo + ((slen * (w + 1)) >> 2);

    float2 a0 = {0.f, 0.f}, a1 = {0.f, 0.f}, a2 = {0.f, 0.f}, a3 = {0.f, 0.f};
    int j = wlo;
    for (; j + 15 < whi; j += 16) {
        int s0 = srcl[j + q], s1 = srcl[j + 4 + q];
        int s2 = srcl[j + 8 + q], s3 = srcl[j + 12 + q];
        uint4 v0 = *(const uint4*)(Tu + (size_t)s0 * 128 + l * 4);
        uint4 v1 = *(const uint4*)(Tu + (size_t)s1 * 128 + l * 4);
        uint4 v2 = *(const uint4*)(Tu + (size_t)s2 * 128 + l * 4);
        uint4 v3 = *(const uint4*)(Tu + (size_t)s3 * 128 + l * 4);
        acc2(a0, v0.x); acc2(a1, v0.y); acc2(a2, v0.z); acc2(a3, v0.w);
        acc2(a0, v1.x); acc2(a1, v1.y); acc2(a2, v1.z); acc2(a3, v1.w);
        acc2(a0, v2.x); acc2(a1, v2.y); acc2(a2, v2.z); acc2(a3, v2.w);
        acc2(a0, v3.x); acc2(a1, v3.y); acc2(a2, v3.z); acc2(a3, v3.w);
    }
    for (; j + 3 < whi; j += 4) {
        int sv = srcl[j + q];
        uint4 v = *(const uint4*)(Tu + (size_t)sv * 128 + l * 4);
        acc2(a0, v.x); acc2(a1, v.y); acc2(a2, v.z); acc2(a3, v.w);
    }
    if (j + q < whi) {
        int sv = srcl[j + q];
        uint4 v = *(const uint4*)(Tu + (size_t)sv * 128 + l * 4);
        acc2(a0, v.x); acc2(a1, v.y); acc2(a2, v.z); acc2(a3, v.w);
    }
    float acc[8] = {a0.x, a0.y, a1.x, a1.y, a2.x, a2.y, a3.x, a3.y};
#pragma unroll
    for (int i = 0; i < 8; ++i) {
        acc[i] += __shfl_xor(acc[i], 16, 64);
        acc[i] += __shfl_xor(acc[i], 32, 64);
    }
    if (q == 0) {
#pragma unroll
        for (int i = 0; i < 8; ++i) red[w][l * 8 + i] = acc[i];
    }
    // o3 partial: 16 row streams (8 segs x 2 rowgroups), rows step 16
    float so = 0.f;
    int ch = t & 127, rg = t >> 7;
    for (int r = n_lo + s * 2 + rg; r < n_hi; r += 16)
        so += b2f(Tu[(size_t)r * 128 + 64 + (ch >> 1)], ch & 1);
    po[rg][ch] = so;
    __syncthreads();
    if (t < 128) {
        float v = red[0][t] + red[1][t] + red[2][t] + red[3][t] + po[0][t] + po[1][t];
        psum[((size_t)g * PSEG + s) * 128 + t] = v;
    }
}

// ---------------- per-graph head: reduce 8 partials, mean, MLP ---------------------

__global__ __launch_bounds__(128) void head_kernel(
    const float* __restrict__ psum, const int* __restrict__ gn,
    const float* __restrict__ W1, const float* __restrict__ b1,
    const float* __restrict__ W2, const float* __restrict__ b2,
    float* __restrict__ out) {
    __shared__ float p[128];
    __shared__ float hid[40];
    int g = blockIdx.x, t = threadIdx.x;
    int cnt = gn[g + 1] - gn[g];
    float sv = 0.f;
#pragma unroll
    for (int k = 0; k < PSEG; ++k) sv += psum[((size_t)g * PSEG + k) * 128 + t];
    p[t] = sv / fmaxf((float)cnt, 1.f);
    __syncthreads();
    if (t < 40) {
        float v = b1[t];
        for (int k = 0; k < 128; ++k) v += p[k] * W1[k * 40 + t];
        hid[t] = v;
    }
    __syncthreads();
    if (t < 10) {
        float v = b2[t];
        for (int j = 0; j < 40; ++j) v += hid[j] * W2[j * 10 + t];
        out[g * 10 + t] = v;
    }
}

// ---------------- launch ----------------

extern "C" void kernel_launch(void* const* d_in, const int* in_sizes, int n_in,
                              void* d_out, int out_size, void* d_ws, size_t ws_size,
                              hipStream_t stream) {
    const float* x   = (const float*)d_in[0];
    const int* ei    = (const int*)d_in[1];
    const int* batch = (const int*)d_in[2];
    const float* Wr1 = (const float*)d_in[3];
    const float* br1 = (const float*)d_in[4];
    const float* Wo1 = (const float*)d_in[5];
    const float* Wr2 = (const float*)d_in[6];
    const float* br2 = (const float*)d_in[7];
    const float* Wo2 = (const float*)d_in[8];
    const float* Wr3 = (const float*)d_in[9];
    const float* br3 = (const float*)d_in[10];
    const float* Wo3 = (const float*)d_in[11];
    const float* W1  = (const float*)d_in[12];
    const float* b1  = (const float*)d_in[13];
    const float* W2  = (const float*)d_in[14];
    const float* b2  = (const float*)d_in[15];
    float* out = (float*)d_out;

    char* ws = (char*)d_ws;
    size_t off = 0;
    auto alloc = [&](size_t bytes) {
        void* p = ws + off;
        off += (bytes + 255) & ~(size_t)255;
        return p;
    };
    int* ofs      = (int*)alloc((NN + 1) * sizeof(int));
    int* bcnt     = (int*)alloc(256 * sizeof(int));
    int* gn       = (int*)alloc((GG + 1) * sizeof(int));
    u16* srcl     = (u16*)alloc((size_t)EE * 2);
    u16* ax       = (u16*)alloc((size_t)NN * 256 * 2);   // cols 0-127 agg, 128-255 x_bf
    u16* ah1      = (u16*)alloc((size_t)NN * 256 * 2);   // cols 0-127 agg(h1), 128-255 h1
    u16* t3o3     = (u16*)alloc((size_t)NN * 256 * 2);   // cols 0-127 t3, 128-255 o3
    float* psum   = (float*)alloc((size_t)GG * PSEG * 128 * sizeof(float));
    u16* BT1      = (u16*)alloc(128 * 256 * 2);
    u16* BT2      = (u16*)alloc(256 * 256 * 2);
    u16* BT3      = (u16*)alloc(256 * 256 * 2);
    float* bias3  = (float*)alloc(256 * sizeof(float));
    // pairs (12.85 MB) overlays t3o3 (25.6 MB): pairs lifetime ends at bfill,
    // t3o3 first written at gemm23.
    u32* pairs = (u32*)t3o3;

    hipMemsetAsync(bcnt, 0, 256 * sizeof(int), stream);

    // CSR pass 1 + x->bf16 + weight prep + graph node-ranges (fused ranges)
    bscatter_prep_kernel<<<SCBLKS + XBLKS + 256 + 3, 256, 0, stream>>>(
        ei, bcnt, pairs, x, ax, Wr1, Wo1, Wr2, Wo2, Wr3, Wo3, br3,
        BT1, BT2, BT3, bias3, batch, gn);
    // CSR pass 2
    bfill_kernel<<<NB, 512, 0, stream>>>(pairs, bcnt, ofs, srcl);

    // conv1
    pull_bf_kernel<<<NN * 64 / 256, 256, 0, stream>>>((const u32*)ax + 64, ofs, srcl, (u32*)ax);
    gemm_bf_kernel<<<dim3(1, 391), 256, 0, stream>>>(ax, BT1, br1, ah1, 256, 128, 1);
    // conv2
    pull_bf_kernel<<<NN * 64 / 256, 256, 0, stream>>>((const u32*)ah1 + 64, ofs, srcl, (u32*)ah1);
    // conv2 GEMM + conv3 GEMM fused: t3o3 = relu(ah1@BT2^T+br2) @ BT3^T + bias3
    gemm23_kernel<<<782, 256, 0, stream>>>(ah1, BT2, br2, BT3, bias3, t3o3);

    // fused h3-aggregation + pool partials (per graph-segment), then head
    pool3_seg_kernel<<<GG * PSEG, 256, 0, stream>>>((const u32*)t3o3, ofs, srcl, gn, psum);
    head_kernel<<<GG, 128, 0, stream>>>(psum, gn, W1, b1, W2, b2, out);
}

// Round 8
// 301.114 us; speedup vs baseline: 1.2464x; 1.1290x over previous
//
#include <hip/hip_runtime.h>
#include <hip/hip_bf16.h>
#include <cstddef>

#define NN 50000
#define EE 1600000
#define GG 512
#define NB 196        // ceil(NN/256) buckets of 256 nodes
#define BSTRIDE 16384 // fixed pairs-region capacity per bucket (max span ~8600)
#define BCAP 10240    // LDS staging per bucket
#define XBLKS 6250    // NN*32/256 x-convert blocks
#define SCBLKS 782    // ceil(EE/2048) bscatter blocks
#define PSEG 8        // edge segments per graph in pool3_f8

typedef unsigned int u32;
typedef unsigned short u16;
typedef __attribute__((ext_vector_type(8))) short frag_ab;   // 8 bf16 = 4 VGPRs
typedef __attribute__((ext_vector_type(4))) float frag_cd;   // 4 fp32 acc
typedef __attribute__((ext_vector_type(2))) float f32x2;

__device__ __forceinline__ void gl_lds16(const void* g, void* l) {
    __builtin_amdgcn_global_load_lds(
        (const __attribute__((address_space(1))) u32*)g,
        (__attribute__((address_space(3))) u32*)l, 16, 0, 0);
}
__device__ __forceinline__ float b2f_lo(u32 v) { return __uint_as_float(v << 16); }
__device__ __forceinline__ float b2f_hi(u32 v) { return __uint_as_float(v & 0xffff0000u); }
__device__ __forceinline__ float b2f(u32 v, int odd) { return odd ? b2f_hi(v) : b2f_lo(v); }
__device__ __forceinline__ u16 f2b(float x) {
    __hip_bfloat16 h = __float2bfloat16(x);
    return *(u16*)&h;
}
__device__ __forceinline__ u32 pack2(float lo, float hi) {
    return ((u32)f2b(hi) << 16) | f2b(lo);
}
// fp8 e4m3 helpers (HW cvt, gfx940+)
__device__ __forceinline__ void accf8(float* a, u32 w) {
    f32x2 p0 = __builtin_amdgcn_cvt_pk_f32_fp8(w, false);
    f32x2 p1 = __builtin_amdgcn_cvt_pk_f32_fp8(w, true);
    a[0] += p0.x; a[1] += p0.y; a[2] += p1.x; a[3] += p1.y;
}
__device__ __forceinline__ u32 pk4_f8(float a, float b, float c, float d) {
    u32 w = __builtin_amdgcn_cvt_pk_fp8_f32(a, b, 0, false);
    return __builtin_amdgcn_cvt_pk_fp8_f32(c, d, w, true);
}

__device__ inline int lower_bound_i(const int* a, int n, int v) {
    int lo = 0, hi = n;
    while (lo < hi) {
        int m = (lo + hi) >> 1;
        if (a[m] < v) lo = m + 1; else hi = m;
    }
    return lo;
}

// Gather model (R0/R1/R2/R7): time ~ distinct 64B lines touched (6.4M at bf16,
// 4.7 cyc/line/CU), invariant to layout and fetch volume. fp8 e4m3 side copies
// of the 3 gathered tensors halve lines -> predicted ~2x on pulls. All GEMM
// operands and o3 stay bf16; fp8 error enters only the neighbor sums.

// ---------------- fused: edge bucket-scatter + x->bf16+fp8 + weight prep + gn ------

__global__ __launch_bounds__(256) void bscatter_prep_kernel(
    const int* __restrict__ ei, int* __restrict__ bcnt, u32* __restrict__ pairs,
    const float* __restrict__ x, u16* __restrict__ ax, u32* __restrict__ x8,
    const float* __restrict__ Wr1, const float* __restrict__ Wo1,
    const float* __restrict__ Wr2, const float* __restrict__ Wo2,
    const float* __restrict__ Wr3, const float* __restrict__ Wo3,
    const float* __restrict__ br3,
    u16* __restrict__ BT1, u16* __restrict__ BT2, u16* __restrict__ BT3,
    float* __restrict__ bias3, const int* __restrict__ batch,
    int* __restrict__ gn) {
    __shared__ int lcnt[NB];
    __shared__ int lbase[NB];
    __shared__ unsigned short lpos[2048];
    int bid = blockIdx.x, t = threadIdx.x;
    if (bid < SCBLKS) {
        int e0 = bid * 2048;
        u32 pk[8];   // packed (src<<8)|(dst&255) stashed across phases
        int bk[8];
        for (int i = t; i < NB; i += 256) lcnt[i] = 0;
        __syncthreads();
#pragma unroll
        for (int i = 0; i < 8; ++i) {
            int e = e0 + i * 256 + t;
            if (e < EE) {
                int dst = ei[EE + e], src = ei[e];
                int b = dst >> 8;
                bk[i] = b;
                pk[i] = ((u32)src << 8) | (u32)(dst & 255);
                lpos[i * 256 + t] = (unsigned short)atomicAdd(&lcnt[b], 1);
            } else bk[i] = -1;
        }
        __syncthreads();
        for (int i = t; i < NB; i += 256) lbase[i] = atomicAdd(&bcnt[i], lcnt[i]);
        __syncthreads();
#pragma unroll
        for (int i = 0; i < 8; ++i) {
            if (bk[i] >= 0) {
                int pos = lbase[bk[i]] + (int)lpos[i * 256 + t];
                pairs[(size_t)bk[i] * BSTRIDE + pos] = pk[i];
            }
        }
    } else if (bid < SCBLKS + XBLKS) {
        int idx = (bid - SCBLKS) * 256 + t;
        int row = idx >> 5, q = idx & 31;
        float4 v = *(const float4*)(x + (size_t)row * 128 + q * 4);
        *(u32*)(ax + (size_t)row * 256 + 128 + q * 4) = pack2(v.x, v.y);
        *(u32*)(ax + (size_t)row * 256 + 128 + q * 4 + 2) = pack2(v.z, v.w);
        x8[(size_t)row * 32 + q] = pk4_f8(v.x, v.y, v.z, v.w);
    } else if (bid < SCBLKS + XBLKS + 256) {
        int m = bid - SCBLKS - XBLKS;   // 0..255 output col
        int k = t;                       // reduction idx
        BT2[m * 256 + k] = f2b(k < 128 ? Wr2[k * 256 + m] : Wo2[(k - 128) * 256 + m]);
        BT3[m * 256 + k] = f2b(m < 128 ? Wr3[k * 128 + m] : Wo3[k * 128 + (m - 128)]);
        if (m < 128)
            BT1[m * 256 + k] = f2b(k < 128 ? Wr1[k * 128 + m] : Wo1[(k - 128) * 128 + m]);
        if (k == 0) bias3[m] = (m < 128) ? 0.f : br3[m - 128];
    } else {
        int g = (bid - SCBLKS - XBLKS - 256) * 256 + t;   // 0..767
        if (g <= GG) gn[g] = lower_bound_i(batch, NN, g);
    }
}

// ---------------- CSR pass 2 (512 threads/block; srcl in u16) ----------------

__global__ __launch_bounds__(512) void bfill_kernel(const u32* __restrict__ pairs,
                                                    const int* __restrict__ bcnt,
                                                    int* __restrict__ ofs,
                                                    u16* __restrict__ srcl) {
    __shared__ int sc[256];
    __shared__ int cnts[256];
    __shared__ int lcnt[256];
    __shared__ int lcur[256];
    __shared__ int lbuf[BCAP];
    int b = blockIdx.x, t = threadIdx.x;
    if (t < 256) {
        int c = (t < NB) ? bcnt[t] : 0;
        cnts[t] = c;
        sc[t] = c;
        lcnt[t] = 0;
    }
    __syncthreads();
    for (int off = 1; off < 256; off <<= 1) {
        int v = (t >= off && t < 256) ? sc[t - off] : 0;
        __syncthreads();
        if (t < 256) sc[t] += v;
        __syncthreads();
    }
    int base = sc[b] - cnts[b];
    int span = cnts[b];
    const u32* pp = pairs + (size_t)b * BSTRIDE;
    for (int j = t; j < span; j += 512) atomicAdd(&lcnt[pp[j] & 255u], 1);
    __syncthreads();
    int nc = 0;
    if (t < 256) {
        nc = lcnt[t];
        sc[t] = nc;
    }
    __syncthreads();
    for (int off = 1; off < 256; off <<= 1) {
        int v = (t >= off && t < 256) ? sc[t - off] : 0;
        __syncthreads();
        if (t < 256) sc[t] += v;
        __syncthreads();
    }
    if (t < 256) {
        int excl = sc[t] - nc;
        int node = b * 256 + t;
        if (node < NN) ofs[node] = base + excl;
        lcur[t] = excl;
    }
    if (b == 0 && t == 256) ofs[NN] = EE;
    __syncthreads();
    for (int j = t; j < span; j += 512) {
        u32 p = pp[j];
        int pos = atomicAdd(&lcur[p & 255u], 1);
        int src = (int)(p >> 8);
        if (pos < BCAP) lbuf[pos] = src;
        else srcl[base + pos] = (u16)src;
    }
    __syncthreads();
    int lim = span < BCAP ? span : BCAP;
    for (int j = t; j < lim; j += 512) srcl[base + j] = (u16)lbuf[j];
}

// ---------------- fp8 pull: 128B rows, 8 edge slots, 32-edge unroll ---------------
// One wave per node. q=lane>>3: edge slot; l=lane&7: 16B group (16 fp8 ch).
// 4 independent gathers in flight; 2 lines/edge (vs 4 at bf16).

__global__ __launch_bounds__(256) void pull_f8_kernel(const u32* __restrict__ X8,
                                                      const int* __restrict__ ofs,
                                                      const u16* __restrict__ srcl,
                                                      u32* __restrict__ outu) {
    int node = (blockIdx.x * 256 + threadIdx.x) >> 6;
    int lane = threadIdx.x & 63;
    int q = lane >> 3, l = lane & 7;
    int lo = ofs[node], hi = ofs[node + 1];
    float acc[16];
#pragma unroll
    for (int i = 0; i < 16; ++i) acc[i] = 0.f;
    int j = lo;
    for (; j + 31 < hi; j += 32) {
        int s0 = srcl[j + q], s1 = srcl[j + 8 + q];
        int s2 = srcl[j + 16 + q], s3 = srcl[j + 24 + q];
        uint4 v0 = *(const uint4*)(X8 + (size_t)s0 * 32 + l * 4);
        uint4 v1 = *(const uint4*)(X8 + (size_t)s1 * 32 + l * 4);
        uint4 v2 = *(const uint4*)(X8 + (size_t)s2 * 32 + l * 4);
        uint4 v3 = *(const uint4*)(X8 + (size_t)s3 * 32 + l * 4);
        accf8(acc + 0, v0.x); accf8(acc + 4, v0.y); accf8(acc + 8, v0.z); accf8(acc + 12, v0.w);
        accf8(acc + 0, v1.x); accf8(acc + 4, v1.y); accf8(acc + 8, v1.z); accf8(acc + 12, v1.w);
        accf8(acc + 0, v2.x); accf8(acc + 4, v2.y); accf8(acc + 8, v2.z); accf8(acc + 12, v2.w);
        accf8(acc + 0, v3.x); accf8(acc + 4, v3.y); accf8(acc + 8, v3.z); accf8(acc + 12, v3.w);
    }
    for (; j + 15 < hi; j += 16) {
        int s0 = srcl[j + q], s1 = srcl[j + 8 + q];
        uint4 v0 = *(const uint4*)(X8 + (size_t)s0 * 32 + l * 4);
        uint4 v1 = *(const uint4*)(X8 + (size_t)s1 * 32 + l * 4);
        accf8(acc + 0, v0.x); accf8(acc + 4, v0.y); accf8(acc + 8, v0.z); accf8(acc + 12, v0.w);
        accf8(acc + 0, v1.x); accf8(acc + 4, v1.y); accf8(acc + 8, v1.z); accf8(acc + 12, v1.w);
    }
    for (; j + 7 < hi; j += 8) {
        int s = srcl[j + q];
        uint4 v = *(const uint4*)(X8 + (size_t)s * 32 + l * 4);
        accf8(acc + 0, v.x); accf8(acc + 4, v.y); accf8(acc + 8, v.z); accf8(acc + 12, v.w);
    }
    if (j + q < hi) {
        int s = srcl[j + q];
        uint4 v = *(const uint4*)(X8 + (size_t)s * 32 + l * 4);
        accf8(acc + 0, v.x); accf8(acc + 4, v.y); accf8(acc + 8, v.z); accf8(acc + 12, v.w);
    }
#pragma unroll
    for (int i = 0; i < 16; ++i) {
        acc[i] += __shfl_xor(acc[i], 8, 64);
        acc[i] += __shfl_xor(acc[i], 16, 64);
        acc[i] += __shfl_xor(acc[i], 32, 64);
    }
    if (q == 0) {
        uint4 r0, r1;
        r0.x = pack2(acc[0], acc[1]);  r0.y = pack2(acc[2], acc[3]);
        r0.z = pack2(acc[4], acc[5]);  r0.w = pack2(acc[6], acc[7]);
        r1.x = pack2(acc[8], acc[9]);  r1.y = pack2(acc[10], acc[11]);
        r1.z = pack2(acc[12], acc[13]); r1.w = pack2(acc[14], acc[15]);
        *(uint4*)(outu + (size_t)node * 128 + l * 8) = r0;
        *(uint4*)(outu + (size_t)node * 128 + l * 8 + 4) = r1;
    }
}

// ---------------- gemm1 (M64 template): h1 = relu([agg|x]@BT1^T + br1) ------------
// Writes h1 bf16 into ah1 cols 128-255 AND fp8 copy into h1f8 (both via the
// swizzled-LDS repack -> coalesced stores).

__global__ __launch_bounds__(256, 3) void gemm1_kernel(
    const u16* __restrict__ A, const u16* __restrict__ BT1,
    const float* __restrict__ br1, u16* __restrict__ C, u32* __restrict__ F8) {
    __shared__ alignas(16) u16 As[64 * 32];    // 4 KB
    __shared__ alignas(16) u16 Bs[128 * 32];   // 8 KB
    __shared__ alignas(16) u16 Hs[64 * 128];   // 16 KB
    const int t = threadIdx.x;
    const int lane = t & 63, w = t >> 6;
    const int quad = lane >> 4, l16 = lane & 15;
    const int row0 = blockIdx.x * 64;

    const int ra = t >> 2, oa = (t & 3) * 8;
    const int garow = min(row0 + ra, NN - 1);
    const size_t gA = (size_t)garow * 256 + oa;
    size_t gB[2];
#pragma unroll
    for (int i = 0; i < 2; ++i) {
        int cbi = i * 256 + t;
        gB[i] = (size_t)(cbi >> 2) * 256 + (cbi & 3) * 8;
    }

    frag_cd acc[8];
#pragma unroll
    for (int i = 0; i < 8; ++i) acc[i] = (frag_cd)0.f;

    for (int kk = 0; kk < 256; kk += 32) {
        __syncthreads();
        gl_lds16(A + gA + kk, &As[t * 8]);
#pragma unroll
        for (int i = 0; i < 2; ++i)
            gl_lds16(BT1 + gB[i] + kk, &Bs[(i * 256 + t) * 8]);
        __syncthreads();
        frag_ab a = *(const frag_ab*)&As[(w * 16 + l16) * 32 + quad * 8];
#pragma unroll
        for (int nt = 0; nt < 8; ++nt) {
            frag_ab b = *(const frag_ab*)&Bs[(nt * 16 + l16) * 32 + quad * 8];
            acc[nt] = __builtin_amdgcn_mfma_f32_16x16x32_bf16(a, b, acc[nt], 0, 0, 0);
        }
    }
#pragma unroll
    for (int nt = 0; nt < 8; ++nt) {
        int col = nt * 16 + l16;
        float bv = br1[col];
#pragma unroll
        for (int r = 0; r < 4; ++r) {
            int lr = w * 16 + quad * 4 + r;
            float v = fmaxf(acc[nt][r] + bv, 0.f);
            Hs[(lr * 128 + col) ^ ((lr & 7) << 3)] = f2b(v);
        }
    }
    __syncthreads();
    const uint4* Hs128 = (const uint4*)Hs;
#pragma unroll
    for (int it = 0; it < 4; ++it) {
        int row = it * 16 + (t >> 4);
        int grp = t & 15;
        uint4 v = Hs128[row * 16 + (grp ^ (row & 7))];
        int grow = row0 + row;
        if (grow < NN) {
            *(uint4*)(C + (size_t)grow * 256 + 128 + grp * 8) = v;
            float f0 = b2f_lo(v.x), f1 = b2f_hi(v.x), f2 = b2f_lo(v.y), f3 = b2f_hi(v.y);
            float f4 = b2f_lo(v.z), f5 = b2f_hi(v.z), f6 = b2f_lo(v.w), f7 = b2f_hi(v.w);
            uint2 w8;
            w8.x = pk4_f8(f0, f1, f2, f3);
            w8.y = pk4_f8(f4, f5, f6, f7);
            *(uint2*)(F8 + (size_t)grow * 32 + grp * 2) = w8;
        }
    }
}

// ---------------- fused GEMM2+GEMM3, M-tile 64, 3 blocks/CU (R7 proven) ------------
// Epilogue additionally emits fp8 t3 copy (cols 0-127) for the pool gather.

__global__ __launch_bounds__(256, 3) void gemm23_kernel(
    const u16* __restrict__ A, const u16* __restrict__ BT2,
    const float* __restrict__ br2, const u16* __restrict__ BT3,
    const float* __restrict__ bias3, u16* __restrict__ C, u32* __restrict__ T8) {
    __shared__ alignas(16) u16 As[64 * 32];    // 4 KB
    __shared__ alignas(16) u16 Bs[256 * 32];   // 16 KB
    __shared__ alignas(16) u16 Hs[64 * 256];   // 32 KB
    const int t = threadIdx.x;
    const int lane = t & 63, w = t >> 6;
    const int quad = lane >> 4, l16 = lane & 15;
    const int row0 = blockIdx.x * 64;

    const int ra = t >> 2, oa = (t & 3) * 8;
    const int garow = min(row0 + ra, NN - 1);
    const size_t gA = (size_t)garow * 256 + oa;
    size_t gB[4];
#pragma unroll
    for (int i = 0; i < 4; ++i) {
        int cbi = i * 256 + t;
        gB[i] = (size_t)(cbi >> 2) * 256 + (cbi & 3) * 8;
    }

    frag_cd acc[16];
#pragma unroll
    for (int i = 0; i < 16; ++i) acc[i] = (frag_cd)0.f;

    // ---- stage 1 ----
    for (int kk = 0; kk < 256; kk += 32) {
        __syncthreads();
        gl_lds16(A + gA + kk, &As[t * 8]);
#pragma unroll
        for (int i = 0; i < 4; ++i)
            gl_lds16(BT2 + gB[i] + kk, &Bs[(i * 256 + t) * 8]);
        __syncthreads();
        frag_ab a = *(const frag_ab*)&As[(w * 16 + l16) * 32 + quad * 8];
#pragma unroll
        for (int nt = 0; nt < 16; ++nt) {
            frag_ab b = *(const frag_ab*)&Bs[(nt * 16 + l16) * 32 + quad * 8];
            acc[nt] = __builtin_amdgcn_mfma_f32_16x16x32_bf16(a, b, acc[nt], 0, 0, 0);
        }
    }
    // park h2 (own-wave rows) in swizzled Hs (bias + relu + bf16 round)
#pragma unroll
    for (int nt = 0; nt < 16; ++nt) {
        int col = nt * 16 + l16;
        float bv = br2[col];
#pragma unroll
        for (int r = 0; r < 4; ++r) {
            int lr = w * 16 + quad * 4 + r;
            float v = fmaxf(acc[nt][r] + bv, 0.f);
            Hs[(lr * 256 + col) ^ ((lr & 7) << 3)] = f2b(v);
        }
    }

    // ---- stage 2 (A from own-wave Hs rows) ----
#pragma unroll
    for (int i = 0; i < 16; ++i) acc[i] = (frag_cd)0.f;
    const int hrow = w * 16 + l16;
    for (int kk = 0; kk < 256; kk += 32) {
        __syncthreads();   // all waves done reading Bs before restage
#pragma unroll
        for (int i = 0; i < 4; ++i)
            gl_lds16(BT3 + gB[i] + kk, &Bs[(i * 256 + t) * 8]);
        __syncthreads();
        frag_ab a = *(const frag_ab*)&Hs[(hrow * 256 + kk + quad * 8) ^
                                         ((hrow & 7) << 3)];
#pragma unroll
        for (int nt = 0; nt < 16; ++nt) {
            frag_ab b = *(const frag_ab*)&Bs[(nt * 16 + l16) * 32 + quad * 8];
            acc[nt] = __builtin_amdgcn_mfma_f32_16x16x32_bf16(a, b, acc[nt], 0, 0, 0);
        }
    }

    // ---- epilogue: repack C tile into Hs (own-wave rows), coalesced store ----
#pragma unroll
    for (int nt = 0; nt < 16; ++nt) {
        int col = nt * 16 + l16;
        float bv = bias3[col];
#pragma unroll
        for (int r = 0; r < 4; ++r) {
            int lr = w * 16 + quad * 4 + r;
            Hs[(lr * 256 + col) ^ ((lr & 7) << 3)] = f2b(acc[nt][r] + bv);
        }
    }
    __syncthreads();
    const uint4* Hs128 = (const uint4*)Hs;
#pragma unroll
    for (int it = 0; it < 8; ++it) {
        int row = it * 8 + (t >> 5);
        int grp = t & 31;
        uint4 v = Hs128[row * 32 + (grp ^ (row & 7))];
        int grow = row0 + row;
        if (grow < NN) {
            *(uint4*)(C + (size_t)grow * 256 + grp * 8) = v;
            if (grp < 16) {   // t3 half -> fp8 copy for the pool gather
                float f0 = b2f_lo(v.x), f1 = b2f_hi(v.x), f2 = b2f_lo(v.y), f3 = b2f_hi(v.y);
                float f4 = b2f_lo(v.z), f5 = b2f_hi(v.z), f6 = b2f_lo(v.w), f7 = b2f_hi(v.w);
                uint2 w8;
                w8.x = pk4_f8(f0, f1, f2, f3);
                w8.y = pk4_f8(f4, f5, f6, f7);
                *(uint2*)(T8 + (size_t)grow * 32 + grp * 2) = w8;
            }
        }
    }
}

// ---------------- pool3_f8: per-(graph,segment) fp8 gather partials ---------------

__global__ __launch_bounds__(256) void pool3_f8_kernel(
    const u32* __restrict__ T8, const u32* __restrict__ Tu,
    const int* __restrict__ ofs, const u16* __restrict__ srcl,
    const int* __restrict__ gn, float* __restrict__ psum) {
    __shared__ float red[4][128];
    __shared__ float po[2][128];
    int gb = blockIdx.x;
    int g = gb >> 3, s = gb & 7;
    int t = threadIdx.x;
    int w = t >> 6, lane = t & 63;
    int q = lane >> 3, l = lane & 7;
    int n_lo = gn[g], n_hi = gn[g + 1];
    int glo = ofs[n_lo], ghi = ofs[n_hi];
    int len = ghi - glo;
    int s_lo = glo + (int)(((long long)len * s) >> 3);
    int s_hi = glo + (int)(((long long)len * (s + 1)) >> 3);
    int slen = s_hi - s_lo;
    int wlo = s_lo + ((slen * w) >> 2);
    int whi = s_lo + ((slen * (w + 1)) >> 2);

    float acc[16];
#pragma unroll
    for (int i = 0; i < 16; ++i) acc[i] = 0.f;
    int j = wlo;
    for (; j + 31 < whi; j += 32) {
        int s0 = srcl[j + q], s1 = srcl[j + 8 + q];
        int s2 = srcl[j + 16 + q], s3 = srcl[j + 24 + q];
        uint4 v0 = *(const uint4*)(T8 + (size_t)s0 * 32 + l * 4);
        uint4 v1 = *(const uint4*)(T8 + (size_t)s1 * 32 + l * 4);
        uint4 v2 = *(const uint4*)(T8 + (size_t)s2 * 32 + l * 4);
        uint4 v3 = *(const uint4*)(T8 + (size_t)s3 * 32 + l * 4);
        accf8(acc + 0, v0.x); accf8(acc + 4, v0.y); accf8(acc + 8, v0.z); accf8(acc + 12, v0.w);
        accf8(acc + 0, v1.x); accf8(acc + 4, v1.y); accf8(acc + 8, v1.z); accf8(acc + 12, v1.w);
        accf8(acc + 0, v2.x); accf8(acc + 4, v2.y); accf8(acc + 8, v2.z); accf8(acc + 12, v2.w);
        accf8(acc + 0, v3.x); accf8(acc + 4, v3.y); accf8(acc + 8, v3.z); accf8(acc + 12, v3.w);
    }
    for (; j + 15 < whi; j += 16) {
        int s0 = srcl[j + q], s1 = srcl[j + 8 + q];
        uint4 v0 = *(const uint4*)(T8 + (size_t)s0 * 32 + l * 4);
        uint4 v1 = *(const uint4*)(T8 + (size_t)s1 * 32 + l * 4);
        accf8(acc + 0, v0.x); accf8(acc + 4, v0.y); accf8(acc + 8, v0.z); accf8(acc + 12, v0.w);
        accf8(acc + 0, v1.x); accf8(acc + 4, v1.y); accf8(acc + 8, v1.z); accf8(acc + 12, v1.w);
    }
    for (; j + 7 < whi; j += 8) {
        int sv = srcl[j + q];
        uint4 v = *(const uint4*)(T8 + (size_t)sv * 32 + l * 4);
        accf8(acc + 0, v.x); accf8(acc + 4, v.y); accf8(acc + 8, v.z); accf8(acc + 12, v.w);
    }
    if (j + q < whi) {
        int sv = srcl[j + q];
        uint4 v = *(const uint4*)(T8 + (size_t)sv * 32 + l * 4);
        accf8(acc + 0, v.x); accf8(acc + 4, v.y); accf8(acc + 8, v.z); accf8(acc + 12, v.w);
    }
#pragma unroll
    for (int i = 0; i < 16; ++i) {
        acc[i] += __shfl_xor(acc[i], 8, 64);
        acc[i] += __shfl_xor(acc[i], 16, 64);
        acc[i] += __shfl_xor(acc[i], 32, 64);
    }
    if (q == 0) {
#pragma unroll
        for (int i = 0; i < 16; ++i) red[w][l * 16 + i] = acc[i];
    }
    // o3 partial (bf16, sequential): 16 row streams, rows step 16
    float so = 0.f;
    int ch = t & 127, rg = t >> 7;
    for (int r = n_lo + s * 2 + rg; r < n_hi; r += 16)
        so += b2f(Tu[(size_t)r * 128 + 64 + (ch >> 1)], ch & 1);
    po[rg][ch] = so;
    __syncthreads();
    if (t < 128) {
        float v = red[0][t] + red[1][t] + red[2][t] + red[3][t] + po[0][t] + po[1][t];
        psum[((size_t)g * PSEG + s) * 128 + t] = v;
    }
}

// ---------------- per-graph head: reduce 8 partials, mean, MLP ---------------------

__global__ __launch_bounds__(128) void head_kernel(
    const float* __restrict__ psum, const int* __restrict__ gn,
    const float* __restrict__ W1, const float* __restrict__ b1,
    const float* __restrict__ W2, const float* __restrict__ b2,
    float* __restrict__ out) {
    __shared__ float p[128];
    __shared__ float hid[40];
    int g = blockIdx.x, t = threadIdx.x;
    int cnt = gn[g + 1] - gn[g];
    float sv = 0.f;
#pragma unroll
    for (int k = 0; k < PSEG; ++k) sv += psum[((size_t)g * PSEG + k) * 128 + t];
    p[t] = sv / fmaxf((float)cnt, 1.f);
    __syncthreads();
    if (t < 40) {
        float v = b1[t];
        for (int k = 0; k < 128; ++k) v += p[k] * W1[k * 40 + t];
        hid[t] = v;
    }
    __syncthreads();
    if (t < 10) {
        float v = b2[t];
        for (int j = 0; j < 40; ++j) v += hid[j] * W2[j * 10 + t];
        out[g * 10 + t] = v;
    }
}

// ---------------- launch ----------------

extern "C" void kernel_launch(void* const* d_in, const int* in_sizes, int n_in,
                              void* d_out, int out_size, void* d_ws, size_t ws_size,
                              hipStream_t stream) {
    const float* x   = (const float*)d_in[0];
    const int* ei    = (const int*)d_in[1];
    const int* batch = (const int*)d_in[2];
    const float* Wr1 = (const float*)d_in[3];
    const float* br1 = (const float*)d_in[4];
    const float* Wo1 = (const float*)d_in[5];
    const float* Wr2 = (const float*)d_in[6];
    const float* br2 = (const float*)d_in[7];
    const float* Wo2 = (const float*)d_in[8];
    const float* Wr3 = (const float*)d_in[9];
    const float* br3 = (const float*)d_in[10];
    const float* Wo3 = (const float*)d_in[11];
    const float* W1  = (const float*)d_in[12];
    const float* b1  = (const float*)d_in[13];
    const float* W2  = (const float*)d_in[14];
    const float* b2  = (const float*)d_in[15];
    float* out = (float*)d_out;

    char* ws = (char*)d_ws;
    size_t off = 0;
    auto alloc = [&](size_t bytes) {
        void* p = ws + off;
        off += (bytes + 255) & ~(size_t)255;
        return p;
    };
    int* ofs      = (int*)alloc((NN + 1) * sizeof(int));
    int* bcnt     = (int*)alloc(256 * sizeof(int));
    int* gn       = (int*)alloc((GG + 1) * sizeof(int));
    u16* srcl     = (u16*)alloc((size_t)EE * 2);
    u16* ax       = (u16*)alloc((size_t)NN * 256 * 2);   // cols 0-127 agg, 128-255 x_bf
    u16* ah1      = (u16*)alloc((size_t)NN * 256 * 2);   // cols 0-127 agg(h1), 128-255 h1
    u16* t3o3     = (u16*)alloc((size_t)NN * 256 * 2);   // cols 0-127 t3, 128-255 o3
    u32* x8       = (u32*)alloc((size_t)NN * 128);       // fp8 x
    u32* h1f8     = (u32*)alloc((size_t)NN * 128);       // fp8 h1
    u32* t3f8     = (u32*)alloc((size_t)NN * 128);       // fp8 t3
    float* psum   = (float*)alloc((size_t)GG * PSEG * 128 * sizeof(float));
    u16* BT1      = (u16*)alloc(128 * 256 * 2);
    u16* BT2      = (u16*)alloc(256 * 256 * 2);
    u16* BT3      = (u16*)alloc(256 * 256 * 2);
    float* bias3  = (float*)alloc(256 * sizeof(float));
    // pairs (12.85 MB) overlays t3o3 (25.6 MB): pairs lifetime ends at bfill,
    // t3o3 first written at gemm23.
    u32* pairs = (u32*)t3o3;

    hipMemsetAsync(bcnt, 0, 256 * sizeof(int), stream);

    // CSR pass 1 + x->bf16+fp8 + weight prep + graph node-ranges
    bscatter_prep_kernel<<<SCBLKS + XBLKS + 256 + 3, 256, 0, stream>>>(
        ei, bcnt, pairs, x, ax, x8, Wr1, Wo1, Wr2, Wo2, Wr3, Wo3, br3,
        BT1, BT2, BT3, bias3, batch, gn);
    // CSR pass 2
    bfill_kernel<<<NB, 512, 0, stream>>>(pairs, bcnt, ofs, srcl);

    // conv1: agg(x) via fp8 gather, then h1 (bf16 + fp8 copy)
    pull_f8_kernel<<<NN * 64 / 256, 256, 0, stream>>>(x8, ofs, srcl, (u32*)ax);
    gemm1_kernel<<<782, 256, 0, stream>>>(ax, BT1, br1, ah1, h1f8);
    // conv2: agg(h1) via fp8 gather
    pull_f8_kernel<<<NN * 64 / 256, 256, 0, stream>>>(h1f8, ofs, srcl, (u32*)ah1);
    // conv2 GEMM + conv3 GEMM fused (emits t3o3 bf16 + t3 fp8 copy)
    gemm23_kernel<<<782, 256, 0, stream>>>(ah1, BT2, br2, BT3, bias3, t3o3, t3f8);

    // fused h3-aggregation + pool partials (fp8 gather), then head
    pool3_f8_kernel<<<GG * PSEG, 256, 0, stream>>>(t3f8, (const u32*)t3o3,
                                                   ofs, srcl, gn, psum);
    head_kernel<<<GG, 128, 0, stream>>>(psum, gn, W1, b1, W2, b2, out);
}